// Round 1
// baseline (1176.722 us; speedup 1.0000x reference)
//
#include <hip/hip_runtime.h>
#include <math.h>

// Problem constants (fixed shapes from reference setup_inputs)
#define NS   32      // batch
#define TS   1024    // time steps
#define KIN  2048    // INPUT_SIZE
#define RED  128     // REDUCED
#define HID  32      // HIDDEN
#define G3   96      // 3*HIDDEN
#define SEQ  8       // x.shape[1] — x data itself is never used

// ws layout (floats): gx[32*1024*96] | W_comb[96*2048] | b_comb[96]
#define GX_FLOATS   (NS * TS * G3)          // 3,145,728
#define WC_FLOATS   (G3 * KIN)              // 196,608

// fea_len may arrive as int32 or int64 depending on harness x64 config.
// int64 little-endian with values < 2^31 => odd int32 words are all zero.
__device__ __forceinline__ int load_len(const int* __restrict__ p, int n) {
    bool is64 = (p[1] == 0) && (p[3] == 0) && (p[5] == 0) && (p[7] == 0);
    if (is64) return (int)((const long long*)p)[n];
    return p[n];
}

__device__ __forceinline__ float fsig(float x) {
    return 1.0f / (1.0f + __expf(-x));
}
__device__ __forceinline__ float ftanh(float x) {
    float ax = fabsf(x);
    float e  = __expf(-2.0f * ax);
    float r  = (1.0f - e) / (1.0f + e);
    return copysignf(r, x);
}

// ---------------------------------------------------------------------------
// K1: W_comb[j][k] = sum_m W_ih[j][m] * W_ann[m][k];  b_comb[j] = b_ih[j] + W_ih[j]·b_ann
// grid 769 x 256: blocks 0..767 cover 96*2048 outputs; block 768 does b_comb.
// ---------------------------------------------------------------------------
__global__ __launch_bounds__(256) void k_prep(
        const float* __restrict__ W_ann, const float* __restrict__ b_ann,
        const float* __restrict__ W_ih,  const float* __restrict__ b_ih,
        float* __restrict__ W_comb, float* __restrict__ b_comb) {
    if (blockIdx.x == 768) {
        int j = threadIdx.x;
        if (j < G3) {
            float acc = b_ih[j];
            #pragma unroll 8
            for (int m = 0; m < RED; ++m) acc += W_ih[j * RED + m] * b_ann[m];
            b_comb[j] = acc;
        }
        return;
    }
    int id = blockIdx.x * 256 + threadIdx.x;   // 0 .. 196607
    int j = id >> 11;          // /2048
    int k = id & (KIN - 1);
    float acc = 0.0f;
    #pragma unroll 8
    for (int m = 0; m < RED; ++m) acc += W_ih[j * RED + m] * W_ann[m * KIN + k];
    W_comb[(size_t)j * KIN + k] = acc;
}

// ---------------------------------------------------------------------------
// K2: gx[n][t][j] = fea[n][t][:] · W_comb[j][:] + b_comb[j], for t-tiles below L[n].
// Tile: 64 t x 96 j, K-tiles of 64. 256 threads, 4t x 6j register tile.
// Thread map: jg = tx & 15 (store coalescing over j), tg = tx >> 4.
// ---------------------------------------------------------------------------
__global__ __launch_bounds__(256) void k_gemm(
        const float* __restrict__ fea, const int* __restrict__ flen,
        const float* __restrict__ W_comb, const float* __restrict__ b_comb,
        float* __restrict__ gx) {
    int n  = blockIdx.y;
    int t0 = blockIdx.x * 64;
    int L  = load_len(flen, n) + SEQ;
    if (t0 >= L) return;   // scan never reads gx at t >= L

    __shared__ float4 feaS[64][17];   // [t][k4], stride 17 float4s (bank spread)
    __shared__ float4 wS[96][17];     // [j][k4]

    int tx = threadIdx.x;
    int jg = tx & 15;     // fast dim -> j (coalesced stores)
    int tg = tx >> 4;     // 0..15

    float acc[4][6];
    #pragma unroll
    for (int i = 0; i < 4; ++i)
        #pragma unroll
        for (int jj = 0; jj < 6; ++jj) acc[i][jj] = 0.0f;

    for (int k0 = 0; k0 < KIN; k0 += 64) {
        __syncthreads();
        // stage fea tile: 64 rows x 16 float4
        #pragma unroll
        for (int p = 0; p < 4; ++p) {
            int fl = tx + p * 256;
            int row = fl >> 4, c4 = fl & 15;
            feaS[row][c4] = *(const float4*)(fea +
                ((size_t)(n * TS + t0 + row)) * KIN + k0 + c4 * 4);
        }
        // stage W tile: 96 rows x 16 float4
        #pragma unroll
        for (int p = 0; p < 6; ++p) {
            int fl = tx + p * 256;
            int row = fl >> 4, c4 = fl & 15;
            wS[row][c4] = *(const float4*)(W_comb + (size_t)row * KIN + k0 + c4 * 4);
        }
        __syncthreads();
        #pragma unroll
        for (int k4 = 0; k4 < 16; ++k4) {
            float4 a[4], w[6];
            #pragma unroll
            for (int i = 0; i < 4; ++i)  a[i] = feaS[tg + 16 * i][k4];
            #pragma unroll
            for (int jj = 0; jj < 6; ++jj) w[jj] = wS[jg + 16 * jj][k4];
            #pragma unroll
            for (int i = 0; i < 4; ++i)
                #pragma unroll
                for (int jj = 0; jj < 6; ++jj)
                    acc[i][jj] += a[i].x * w[jj].x + a[i].y * w[jj].y +
                                  a[i].z * w[jj].z + a[i].w * w[jj].w;
        }
    }
    #pragma unroll
    for (int i = 0; i < 4; ++i) {
        int t = t0 + tg + 16 * i;
        #pragma unroll
        for (int jj = 0; jj < 6; ++jj) {
            int j = jg + 16 * jj;
            gx[((size_t)(n * TS + t)) * G3 + j] = acc[i][jj] + b_comb[j];
        }
    }
}

// ---------------------------------------------------------------------------
// K3: GRU scan + q + masked mean. One wave (64 threads) per sample.
// lane = kh*32 + j: lane handles hidden unit j, K-half kh (k in [16kh,16kh+16)).
// W_hh rows r=j, z=32+j, n=64+j held in registers (48 floats/lane).
// h broadcast through LDS; shfl_xor(32) combines K-halves; both halves compute
// gates redundantly; kh==0 writes h and accumulates q.
// ---------------------------------------------------------------------------
__global__ __launch_bounds__(64) void k_scan(
        const float* __restrict__ gx, const int* __restrict__ flen,
        const float* __restrict__ W_hh, const float* __restrict__ b_hh,
        const float* __restrict__ W_q,  const float* __restrict__ b_q,
        float* __restrict__ out) {
    int n    = blockIdx.x;
    int lane = threadIdx.x;
    int j    = lane & 31;
    int kh   = lane >> 5;
    int L    = load_len(flen, n) + SEQ;

    // per-lane recurrent weights (k-half)
    float wr[16], wz[16], wn[16];
    {
        const float4* Wr4 = (const float4*)(W_hh + (size_t)(j)      * HID + kh * 16);
        const float4* Wz4 = (const float4*)(W_hh + (size_t)(32 + j) * HID + kh * 16);
        const float4* Wn4 = (const float4*)(W_hh + (size_t)(64 + j) * HID + kh * 16);
        #pragma unroll
        for (int p = 0; p < 4; ++p) {
            float4 v;
            v = Wr4[p]; wr[4*p] = v.x; wr[4*p+1] = v.y; wr[4*p+2] = v.z; wr[4*p+3] = v.w;
            v = Wz4[p]; wz[4*p] = v.x; wz[4*p+1] = v.y; wz[4*p+2] = v.z; wz[4*p+3] = v.w;
            v = Wn4[p]; wn[4*p] = v.x; wn[4*p+1] = v.y; wn[4*p+2] = v.z; wn[4*p+3] = v.w;
        }
    }
    float br = b_hh[j], bz = b_hh[32 + j], bn = b_hh[64 + j];
    float wq = W_q[j];
    float bq = b_q[0];

    __shared__ __align__(16) float hs[HID];
    if (kh == 0) hs[j] = 0.0f;
    __syncthreads();

    const float* gxn = gx + (size_t)n * TS * G3;
    float xr = gxn[j], xz = gxn[32 + j], xn_ = gxn[64 + j];   // t = 0
    float qacc = 0.0f;

    for (int t = 0; t < L; ++t) {
        // read h_t (broadcast; my K-half)
        float hv[16];
        {
            const float4* hs4 = (const float4*)(hs + kh * 16);
            #pragma unroll
            for (int p = 0; p < 4; ++p) {
                float4 v = hs4[p];
                hv[4*p] = v.x; hv[4*p+1] = v.y; hv[4*p+2] = v.z; hv[4*p+3] = v.w;
            }
        }
        float hprev = hs[j];

        // prefetch next step's gx (t+1 <= 1023 always in-bounds; unused if t+1==L)
        const float* gxt = gxn + (size_t)(t + 1) * G3;
        float nxr = gxt[j], nxz = gxt[32 + j], nxn = gxt[64 + j];

        // half-K dots (2 accumulators per gate to shorten chains)
        float gr0 = 0.f, gr1 = 0.f, gz0 = 0.f, gz1 = 0.f, gn0 = 0.f, gn1 = 0.f;
        #pragma unroll
        for (int i = 0; i < 16; i += 2) {
            gr0 += wr[i] * hv[i];     gr1 += wr[i+1] * hv[i+1];
            gz0 += wz[i] * hv[i];     gz1 += wz[i+1] * hv[i+1];
            gn0 += wn[i] * hv[i];     gn1 += wn[i+1] * hv[i+1];
        }
        float gr = gr0 + gr1, gz = gz0 + gz1, gn = gn0 + gn1;
        gr += __shfl_xor(gr, 32, 64);
        gz += __shfl_xor(gz, 32, 64);
        gn += __shfl_xor(gn, 32, 64);

        float r    = fsig(xr + gr + br);
        float z    = fsig(xz + gz + bz);
        float nng  = ftanh(xn_ + r * (gn + bn));
        float hnew = (1.0f - z) * nng + z * hprev;

        __syncthreads();                       // everyone done reading hs
        if (kh == 0) { hs[j] = hnew; qacc += wq * hnew; }
        __syncthreads();                       // write visible

        xr = nxr; xz = nxz; xn_ = nxn;
    }

    // reduce qacc over the wave (kh==1 lanes hold 0)
    #pragma unroll
    for (int off = 32; off > 0; off >>= 1) qacc += __shfl_xor(qacc, off, 64);
    if (lane == 0) out[n] = qacc / (float)L + bq;
}

// ---------------------------------------------------------------------------
extern "C" void kernel_launch(void* const* d_in, const int* in_sizes, int n_in,
                              void* d_out, int out_size, void* d_ws, size_t ws_size,
                              hipStream_t stream) {
    // setup_inputs order: x, fea, fea_len, W_ann, b_ann, W_ih, W_hh, b_ih, b_hh, W_q, b_q
    const float* fea   = (const float*)d_in[1];
    const int*   flen  = (const int*)  d_in[2];
    const float* W_ann = (const float*)d_in[3];
    const float* b_ann = (const float*)d_in[4];
    const float* W_ih  = (const float*)d_in[5];
    const float* W_hh  = (const float*)d_in[6];
    const float* b_ih  = (const float*)d_in[7];
    const float* b_hh  = (const float*)d_in[8];
    const float* W_q   = (const float*)d_in[9];
    const float* b_q   = (const float*)d_in[10];
    float* out = (float*)d_out;

    float* ws     = (float*)d_ws;
    float* gx     = ws;                       // 12.58 MB
    float* W_comb = ws + GX_FLOATS;           // 768 KB
    float* b_comb = W_comb + WC_FLOATS;       // 384 B

    k_prep<<<769, 256, 0, stream>>>(W_ann, b_ann, W_ih, b_ih, W_comb, b_comb);

    dim3 g2(TS / 64, NS);                     // (16 t-tiles, 32 samples)
    k_gemm<<<g2, 256, 0, stream>>>(fea, flen, W_comb, b_comb, gx);

    k_scan<<<NS, 64, 0, stream>>>(gx, flen, W_hh, b_hh, W_q, b_q, out);
}

// Round 2
// 1135.128 us; speedup vs baseline: 1.0366x; 1.0366x over previous
//
#include <hip/hip_runtime.h>
#include <math.h>

// Problem constants (fixed shapes from reference setup_inputs)
#define NS   32      // batch
#define TS   1024    // time steps
#define KIN  2048    // INPUT_SIZE
#define RED  128     // REDUCED
#define HID  32      // HIDDEN
#define G3   96      // 3*HIDDEN
#define SEQ  8       // x.shape[1] — x data itself is never used

#define GX_FLOATS   (NS * TS * G3)          // 3,145,728 per partial buffer
#define WC_FLOATS   (G3 * KIN)              // 196,608

// fea_len may arrive as int32 or int64. int64 little-endian with values
// < 2^31 => odd int32 words are all zero.
__device__ __forceinline__ int load_len(const int* __restrict__ p, int n) {
    bool is64 = (p[1] == 0) && (p[3] == 0) && (p[5] == 0) && (p[7] == 0);
    if (is64) return (int)((const long long*)p)[n];
    return p[n];
}

__device__ __forceinline__ float fsig(float x) {
    return 1.0f / (1.0f + __expf(-x));
}
__device__ __forceinline__ float ftanh(float x) {
    float ax = fabsf(x);
    float e  = __expf(-2.0f * ax);
    float r  = (1.0f - e) / (1.0f + e);
    return copysignf(r, x);
}

// ---------------------------------------------------------------------------
// K1: W_comb[j][k] = sum_m W_ih[j][m] * W_ann[m][k];  b_comb[j] = b_ih[j] + W_ih[j]·b_ann
// ---------------------------------------------------------------------------
__global__ __launch_bounds__(256) void k_prep(
        const float* __restrict__ W_ann, const float* __restrict__ b_ann,
        const float* __restrict__ W_ih,  const float* __restrict__ b_ih,
        float* __restrict__ W_comb, float* __restrict__ b_comb) {
    if (blockIdx.x == 768) {
        int j = threadIdx.x;
        if (j < G3) {
            float acc = b_ih[j];
            #pragma unroll 8
            for (int m = 0; m < RED; ++m) acc += W_ih[j * RED + m] * b_ann[m];
            b_comb[j] = acc;
        }
        return;
    }
    int id = blockIdx.x * 256 + threadIdx.x;   // 0 .. 196607
    int j = id >> 11;          // /2048
    int k = id & (KIN - 1);
    float acc = 0.0f;
    #pragma unroll 8
    for (int m = 0; m < RED; ++m) acc += W_ih[j * RED + m] * W_ann[m * KIN + k];
    W_comb[(size_t)j * KIN + k] = acc;
}

// ---------------------------------------------------------------------------
// K2: gx_partial[ks][n][t][j] = fea[n][t][kslice] · W_comb[j][kslice] (+b_comb if ks==0)
// Tile: 64 t x 96 j, K-chunks of 64, KS-way K-split (one partial buffer per ks).
// grid (NS, 16*KS): bx = n (fastest -> CU balance), by = tt + 16*ks.
// Register-prefetch double buffering: next chunk's global loads issued before
// the compute on the current LDS tile.
// ---------------------------------------------------------------------------
template<int KS>
__global__ __launch_bounds__(256) void k_gemm(
        const float* __restrict__ fea, const int* __restrict__ flen,
        const float* __restrict__ W_comb, const float* __restrict__ b_comb,
        float* __restrict__ gx) {
    const int n  = blockIdx.x;
    const int by = blockIdx.y;
    const int tt = by & 15;
    const int ks = by >> 4;
    const int t0 = tt * 64;
    const int L  = load_len(flen, n) + SEQ;
    if (t0 >= L) return;   // scan never reads gx at t >= L

    const int KC     = KIN / KS;       // K elements this block covers
    const int NCH    = KC / 64;        // 64-wide chunks
    const int k_base = ks * KC;

    __shared__ float4 feaS[64][17];    // [t][k4], +1 float4 pad
    __shared__ float4 wS[96][17];      // [j][k4]

    const int tx = threadIdx.x;
    const int jg = tx & 15;            // fast dim -> j (coalesced stores)
    const int tg = tx >> 4;            // 0..15

    float4 pf[4], pw[6];
    // prefetch chunk 0
    {
        int k0 = k_base;
        #pragma unroll
        for (int p = 0; p < 4; ++p) {
            int fl = tx + p * 256; int row = fl >> 4, c4 = fl & 15;
            pf[p] = *(const float4*)(fea + ((size_t)(n * TS + t0 + row)) * KIN + k0 + c4 * 4);
        }
        #pragma unroll
        for (int p = 0; p < 6; ++p) {
            int fl = tx + p * 256; int row = fl >> 4, c4 = fl & 15;
            pw[p] = *(const float4*)(W_comb + (size_t)row * KIN + k0 + c4 * 4);
        }
    }

    float acc[4][6];
    #pragma unroll
    for (int i = 0; i < 4; ++i)
        #pragma unroll
        for (int jj = 0; jj < 6; ++jj) acc[i][jj] = 0.0f;

    for (int kc = 0; kc < NCH; ++kc) {
        __syncthreads();               // prior readers done with LDS
        #pragma unroll
        for (int p = 0; p < 4; ++p) { int fl = tx + p * 256; feaS[fl >> 4][fl & 15] = pf[p]; }
        #pragma unroll
        for (int p = 0; p < 6; ++p) { int fl = tx + p * 256; wS[fl >> 4][fl & 15] = pw[p]; }
        __syncthreads();
        if (kc + 1 < NCH) {            // issue next chunk's loads; they fly over compute
            int k0 = k_base + (kc + 1) * 64;
            #pragma unroll
            for (int p = 0; p < 4; ++p) {
                int fl = tx + p * 256; int row = fl >> 4, c4 = fl & 15;
                pf[p] = *(const float4*)(fea + ((size_t)(n * TS + t0 + row)) * KIN + k0 + c4 * 4);
            }
            #pragma unroll
            for (int p = 0; p < 6; ++p) {
                int fl = tx + p * 256; int row = fl >> 4, c4 = fl & 15;
                pw[p] = *(const float4*)(W_comb + (size_t)row * KIN + k0 + c4 * 4);
            }
        }
        #pragma unroll
        for (int k4 = 0; k4 < 16; ++k4) {
            float4 a[4], w[6];
            #pragma unroll
            for (int i = 0; i < 4; ++i)  a[i] = feaS[tg + 16 * i][k4];
            #pragma unroll
            for (int jj = 0; jj < 6; ++jj) w[jj] = wS[jg + 16 * jj][k4];
            #pragma unroll
            for (int i = 0; i < 4; ++i)
                #pragma unroll
                for (int jj = 0; jj < 6; ++jj)
                    acc[i][jj] += a[i].x * w[jj].x + a[i].y * w[jj].y +
                                  a[i].z * w[jj].z + a[i].w * w[jj].w;
        }
    }

    float* gxo = gx + (size_t)ks * GX_FLOATS;
    #pragma unroll
    for (int i = 0; i < 4; ++i) {
        int t = t0 + tg + 16 * i;
        #pragma unroll
        for (int jj = 0; jj < 6; ++jj) {
            int j = jg + 16 * jj;
            float v = acc[i][jj];
            if (ks == 0) v += b_comb[j];
            gxo[((size_t)(n * TS + t)) * G3 + j] = v;
        }
    }
}

// ---------------------------------------------------------------------------
// K3: GRU scan + q + masked mean. One wave per sample, NO LDS round-trip:
// after shfl_xor both K-halves hold bitwise-identical gate sums, so hnew is
// identical in lane j and lane j+32. hv[16] (the lane's K-half slice of h)
// is refreshed with 16 ds_bpermute reads of hnew from lanes 0..31.
// gx prefetch distance 2 (values combined across KS partials at USE time so
// the loads stay in flight).
// ---------------------------------------------------------------------------
template<int KS>
__global__ __launch_bounds__(64) void k_scan(
        const float* __restrict__ gx, const int* __restrict__ flen,
        const float* __restrict__ W_hh, const float* __restrict__ b_hh,
        const float* __restrict__ W_q,  const float* __restrict__ b_q,
        float* __restrict__ out) {
    const int n    = blockIdx.x;
    const int lane = threadIdx.x;
    const int j    = lane & 31;
    const int kh   = lane >> 5;
    const int L    = load_len(flen, n) + SEQ;
    const int sbase = kh << 4;

    // per-lane recurrent weights (this lane's K-half of rows r=j, z=32+j, n=64+j)
    float wr[16], wz[16], wn[16];
    {
        const float4* Wr4 = (const float4*)(W_hh + (size_t)(j)      * HID + sbase);
        const float4* Wz4 = (const float4*)(W_hh + (size_t)(32 + j) * HID + sbase);
        const float4* Wn4 = (const float4*)(W_hh + (size_t)(64 + j) * HID + sbase);
        #pragma unroll
        for (int p = 0; p < 4; ++p) {
            float4 v;
            v = Wr4[p]; wr[4*p] = v.x; wr[4*p+1] = v.y; wr[4*p+2] = v.z; wr[4*p+3] = v.w;
            v = Wz4[p]; wz[4*p] = v.x; wz[4*p+1] = v.y; wz[4*p+2] = v.z; wz[4*p+3] = v.w;
            v = Wn4[p]; wn[4*p] = v.x; wn[4*p+1] = v.y; wn[4*p+2] = v.z; wn[4*p+3] = v.w;
        }
    }
    const float br = b_hh[j], bz = b_hh[32 + j], bn = b_hh[64 + j];
    const float wq = W_q[j];
    const float bq = b_q[0];

    const float* g0 = gx + (size_t)n * TS * G3;

    // prefetch ring, distance 2; raw partial values, combined at use
    float a0[3 * KS], a1[3 * KS];
    auto ldslot = [&](float* s, int t) {
        const float* p = g0 + (size_t)t * G3;
        s[0] = p[j]; s[1] = p[32 + j]; s[2] = p[64 + j];
        if (KS == 2) {
            const float* q = p + GX_FLOATS;
            s[3] = q[j]; s[4] = q[32 + j]; s[5] = q[64 + j];
        }
    };
    ldslot(a0, 0);
    ldslot(a1, 1);          // L >= 8, always valid

    float hv[16];
    #pragma unroll
    for (int i = 0; i < 16; ++i) hv[i] = 0.0f;
    float h = 0.0f, qacc = 0.0f;

    for (int t = 0; t < L; ++t) {
        float xr = a0[0], xz = a0[1], xn = a0[2];
        if (KS == 2) { xr += a0[3]; xz += a0[4]; xn += a0[5]; }
        #pragma unroll
        for (int q = 0; q < 3 * KS; ++q) a0[q] = a1[q];
        int tp = t + 2; if (tp > TS - 1) tp = TS - 1;   // stay inside this sample
        ldslot(a1, tp);

        // half-K dots (2 accumulators per gate to shorten chains)
        float gr0 = 0.f, gr1 = 0.f, gz0 = 0.f, gz1 = 0.f, gn0 = 0.f, gn1 = 0.f;
        #pragma unroll
        for (int i = 0; i < 16; i += 2) {
            gr0 += wr[i] * hv[i];     gr1 += wr[i+1] * hv[i+1];
            gz0 += wz[i] * hv[i];     gz1 += wz[i+1] * hv[i+1];
            gn0 += wn[i] * hv[i];     gn1 += wn[i+1] * hv[i+1];
        }
        float gr = gr0 + gr1, gz = gz0 + gz1, gn = gn0 + gn1;
        gr += __shfl_xor(gr, 32, 64);
        gz += __shfl_xor(gz, 32, 64);
        gn += __shfl_xor(gn, 32, 64);

        float r    = fsig(xr + gr + br);
        float z    = fsig(xz + gz + bz);
        float nng  = ftanh(xn + r * (gn + bn));
        float hnew = (1.0f - z) * nng + z * h;
        h = hnew;
        qacc += wq * hnew;

        // refresh hv from lanes 0..31 (hnew identical in both halves)
        #pragma unroll
        for (int i = 0; i < 16; ++i) hv[i] = __shfl(hnew, sbase + i, 64);
    }

    // every j counted twice (kh=0 and kh=1 lanes hold identical streams)
    #pragma unroll
    for (int off = 32; off > 0; off >>= 1) qacc += __shfl_xor(qacc, off, 64);
    if (lane == 0) out[n] = qacc * 0.5f / (float)L + bq;
}

// ---------------------------------------------------------------------------
extern "C" void kernel_launch(void* const* d_in, const int* in_sizes, int n_in,
                              void* d_out, int out_size, void* d_ws, size_t ws_size,
                              hipStream_t stream) {
    // setup_inputs order: x, fea, fea_len, W_ann, b_ann, W_ih, W_hh, b_ih, b_hh, W_q, b_q
    const float* fea   = (const float*)d_in[1];
    const int*   flen  = (const int*)  d_in[2];
    const float* W_ann = (const float*)d_in[3];
    const float* b_ann = (const float*)d_in[4];
    const float* W_ih  = (const float*)d_in[5];
    const float* W_hh  = (const float*)d_in[6];
    const float* b_ih  = (const float*)d_in[7];
    const float* b_hh  = (const float*)d_in[8];
    const float* W_q   = (const float*)d_in[9];
    const float* b_q   = (const float*)d_in[10];
    float* out = (float*)d_out;

    float* ws = (float*)d_ws;
    size_t need2 = ((size_t)2 * GX_FLOATS + WC_FLOATS + 256) * sizeof(float);
    bool ks2 = ws_size >= need2;     // ws_size fixed per session -> same path every call

    if (ks2) {
        float* gx     = ws;                          // 2 partial buffers, 25.2 MB
        float* W_comb = ws + 2 * GX_FLOATS;
        float* b_comb = W_comb + WC_FLOATS;
        k_prep<<<769, 256, 0, stream>>>(W_ann, b_ann, W_ih, b_ih, W_comb, b_comb);
        dim3 g2(NS, 32);                             // bx=n fastest, by=tt+16*ks
        k_gemm<2><<<g2, 256, 0, stream>>>(fea, flen, W_comb, b_comb, gx);
        k_scan<2><<<NS, 64, 0, stream>>>(gx, flen, W_hh, b_hh, W_q, b_q, out);
    } else {
        float* gx     = ws;                          // 12.6 MB
        float* W_comb = ws + GX_FLOATS;
        float* b_comb = W_comb + WC_FLOATS;
        k_prep<<<769, 256, 0, stream>>>(W_ann, b_ann, W_ih, b_ih, W_comb, b_comb);
        dim3 g2(NS, 16);
        k_gemm<1><<<g2, 256, 0, stream>>>(fea, flen, W_comb, b_comb, gx);
        k_scan<1><<<NS, 64, 0, stream>>>(gx, flen, W_hh, b_hh, W_q, b_q, out);
    }
}